// Round 18
// baseline (65.563 us; speedup 1.0000x reference)
//
#include <hip/hip_runtime.h>
#include <hip/hip_bf16.h>

#define NN 32768
#define GG 256
#define NPG 128
#define EE 262144

using s16x4 = __attribute__((ext_vector_type(4))) short;
using s16x8 = __attribute__((ext_vector_type(8))) short;
using f16x8 = __attribute__((ext_vector_type(8))) _Float16;
using f32x4 = __attribute__((ext_vector_type(4))) float;

__device__ __forceinline__ short f2h(float f) {
    _Float16 h = (_Float16)f;
    return __builtin_bit_cast(short, h);
}
__device__ __forceinline__ f16x8 ash(s16x8 v) { return __builtin_bit_cast(f16x8, v); }

// ---------------- pre-pass: edge bucketing + W/Wl pack (112 blocks) ---------
// blocks 0..63: hierarchical edge scatter; 64..95: W B-frag; 96..111: Wl.
// B-frag chunk: ci=(kb*16+cn)*64+lane, lane=(c%16)|(((k%32)/8)<<4), elem=k%8

__global__ __launch_bounds__(1024) void k_pre(
    const int* __restrict__ ei, int* __restrict__ pos, unsigned* __restrict__ ebuf,
    const float* __restrict__ W0, const float* __restrict__ W1,
    const float* __restrict__ W2, const float* __restrict__ W3,
    const float* __restrict__ Wl,
    short* __restrict__ Wp, float* __restrict__ Wlp)
{
    const int b = blockIdx.x;
    const int tid = threadIdx.x;
    if (b < 64) {
        __shared__ int cnt[256];
        __shared__ int base[256];
        if (tid < 256) cnt[tid] = 0;
        __syncthreads();
        int g[4], r[4];
        unsigned pk[4];
#pragma unroll
        for (int it = 0; it < 4; ++it) {
            int e = b * 4096 + it * 1024 + tid;
            int s = ei[e], d = ei[EE + e];
            g[it] = d >> 7;
            pk[it] = (unsigned)(((d & 127) << 8) | (s & 127));
            r[it] = atomicAdd(&cnt[g[it]], 1);
        }
        __syncthreads();
        if (tid < 256) {
            int c = cnt[tid];
            base[tid] = (c > 0) ? atomicAdd(&pos[tid], c) : 0;
        }
        __syncthreads();
#pragma unroll
        for (int it = 0; it < 4; ++it) {
            int p = base[g[it]] + r[it];
            if (p < 2048) ebuf[g[it] * 2048 + p] = pk[it];
        }
    } else if (b < 96) {
        int t = (b - 64) * 1024 + tid;           // 32768
        int mat = t >> 13, ci = t & 8191;
        const float* W = (mat == 0) ? W0 : (mat == 1) ? W1 : (mat == 2) ? W2 : W3;
        int lane = ci & 63, t2 = ci >> 6;
        int cn = t2 & 15, kb = t2 >> 4;
        int c = cn * 16 + (lane & 15);
        int k0 = kb * 32 + (lane >> 4) * 8;
        s16x8 o;
#pragma unroll
        for (int j = 0; j < 8; ++j) o[j] = f2h(W[(size_t)(k0 + j) * 256 + c]);
        *(s16x8*)(Wp + ((size_t)mat * 8192 + ci) * 8) = o;
    } else {
        int t = (b - 96) * 1024 + tid;           // 16384
        int lane = t & 63, tile = t >> 6;
        int db = tile >> 4, eb = tile & 15;
        int q = lane >> 4, ce = lane & 15;
        float* dst = Wlp + (size_t)t * 8;
#pragma unroll
        for (int r = 0; r < 4; ++r)
#pragma unroll
            for (int cls = 0; cls < 2; ++cls)
                dst[r * 2 + cls] = Wl[(((size_t)(db * 16 + q * 4 + r) * 256) + eb * 16 + ce) * 2 + cls];
    }
}

// ---------------- half-phase: scatter H(cb) -> bh, PROP 4x2, epilogue -------
// (r12/r16-proven cb-body, factored out)
// MODE 0: bias+relu -> act A-frag image in dstImg
// MODE 1: raw conv -> no-max register softmax -> B-frag image in dstImg
// MODE 2: bias+relu -> B-frag image in dstImg

template<int MODE>
__device__ __forceinline__ void half_phase(
    const f32x4 (&acc)[4][4], int cb, short* dstImg, short* bh,
    const s16x8 (&agf)[2][4], const float* __restrict__ bias, int tid)
{
    const int lane = tid & 63, w = tid >> 6, wr = w >> 2, wc = w & 3;
    const int lq = lane >> 4, lm = lane & 15;

    __syncthreads();                   // bh free (and all GEMM reads done)
#pragma unroll
    for (int m = 0; m < 4; ++m)
#pragma unroll
        for (int n = 0; n < 2; ++n) {
            f32x4 hv4 = acc[m][cb * 2 + n];
            int c = wc * 32 + n * 16 + lm;
            int rhi = wr * 2 + (m >> 1);
            int rmid = (m & 1) * 2 + (lq >> 1);
            int idx = ((c >> 4) * 4 + rhi) * 64 + (lm | (rmid << 4));
            s16x4 hv;
            hv[0] = f2h(hv4[0]); hv[1] = f2h(hv4[1]);
            hv[2] = f2h(hv4[2]); hv[3] = f2h(hv4[3]);
            *(s16x4*)&bh[idx * 8 + (lq & 1) * 4] = hv;
        }
    __syncthreads();
    const int pr4 = w >> 1, pc2 = w & 1;
    f32x4 acc2[2][4];
#pragma unroll
    for (int m = 0; m < 2; ++m)
#pragma unroll
        for (int n = 0; n < 4; ++n) acc2[m][n] = (f32x4){0.f, 0.f, 0.f, 0.f};
#pragma unroll
    for (int kb = 0; kb < 4; ++kb) {
        s16x8 bf2[4];
#pragma unroll
        for (int n = 0; n < 4; ++n)
            bf2[n] = *(const s16x8*)(bh + (((pc2 * 4 + n) * 4 + kb) * 64 + lane) * 8);
#pragma unroll
        for (int m = 0; m < 2; ++m)
#pragma unroll
            for (int n = 0; n < 4; ++n)
                acc2[m][n] = __builtin_amdgcn_mfma_f32_16x16x32_f16(ash(agf[m][kb]), ash(bf2[n]), acc2[m][n], 0, 0, 0);
    }
    // rows nr = pr4*32 + m*16 + lq*4 + r ; cols cg = cb*128 + pc2*64 + n*16 + lm

    if constexpr (MODE == 0) {
#pragma unroll
        for (int m = 0; m < 2; ++m)
#pragma unroll
            for (int n = 0; n < 4; ++n) {
                float bn = bias[cb * 128 + pc2 * 64 + n * 16 + lm];
#pragma unroll
                for (int r = 0; r < 4; ++r) {
                    float v = fmaxf(acc2[m][n][r] + bn, 0.f);
                    int nr = pr4 * 32 + m * 16 + lq * 4 + r;
                    int cg = cb * 128 + pc2 * 64 + n * 16 + lm;
                    int idx = ((cg >> 5) * 8 + (nr >> 4)) * 64 + ((nr & 15) | (((cg & 31) >> 3) << 4));
                    dstImg[idx * 8 + (cg & 7)] = f2h(v);
                }
            }
    } else if constexpr (MODE == 2) {
#pragma unroll
        for (int m = 0; m < 2; ++m)
#pragma unroll
            for (int n = 0; n < 4; ++n) {
                float bn = bias[cb * 128 + pc2 * 64 + n * 16 + lm];
                s16x4 ov;
#pragma unroll
                for (int r = 0; r < 4; ++r) ov[r] = f2h(fmaxf(acc2[m][n][r] + bn, 0.f));
                int cn2 = cb * 8 + pc2 * 4 + n;
                int chunk = (cn2 * 4 + pr4) * 64 + (lm | ((m * 2 + (lq >> 1)) << 4));
                *(s16x4*)(dstImg + chunk * 8 + (lq & 1) * 4) = ov;
            }
    } else {  // MODE 1: segment-softmax, no max subtraction (values bounded)
        __syncthreads();               // PROP bh reads done -> red usable
        float* red = (float*)bh;
        float ev[2][4][4];
        float ps[4] = {0.f, 0.f, 0.f, 0.f};
#pragma unroll
        for (int m = 0; m < 2; ++m)
#pragma unroll
            for (int n = 0; n < 4; ++n)
#pragma unroll
                for (int r = 0; r < 4; ++r) {
                    float e = __expf(acc2[m][n][r]);
                    ev[m][n][r] = e; ps[n] += e;
                }
#pragma unroll
        for (int n = 0; n < 4; ++n) {
            ps[n] += __shfl_xor(ps[n], 16);
            ps[n] += __shfl_xor(ps[n], 32);
        }
        if (lq == 0) {
#pragma unroll
            for (int n = 0; n < 4; ++n)
                red[pr4 * 128 + pc2 * 64 + n * 16 + lm] = ps[n];
        }
        __syncthreads();
#pragma unroll
        for (int m = 0; m < 2; ++m)
#pragma unroll
            for (int n = 0; n < 4; ++n) {
                int c = pc2 * 64 + n * 16 + lm;
                float sinv = 1.0f / (red[c] + red[128 + c] + red[256 + c] + red[384 + c]);
                s16x4 ov;
#pragma unroll
                for (int r = 0; r < 4; ++r) ov[r] = f2h(ev[m][n][r] * sinv);
                int cn2 = cb * 8 + pc2 * 4 + n;
                int chunk = (cn2 * 4 + pr4) * 64 + (lm | ((m * 2 + (lq >> 1)) << 4));
                *(s16x4*)(dstImg + chunk * 8 + (lq & 1) * 4) = ov;
            }
    }
}

// ---------------- merged conv stage: both branches' GEMMs in one phase ------
// 2x independent accumulator chains (accA, accX) -> 2x MFMA ILP per phase.
// SHARED=true: srcX == srcA, A-operand loaded once (stages 0+2 share X).
// In-place safe: all GEMM reads complete before the first half_phase barrier;
// branch-A half_phases never write srcX's buffer; branch-X writes after.

template<int MODE_A, int MODE_X, bool SHARED>
__device__ __forceinline__ void conv_merged(
    const short* srcA, const short* srcX, short* dstA, short* dstX,
    short* bh, const short* __restrict__ WpA, const short* __restrict__ WpX,
    const s16x8 (&agf)[2][4], const float* __restrict__ biasA,
    const float* __restrict__ biasX, int tid)
{
    const int lane = tid & 63, w = tid >> 6, wr = w >> 2, wc = w & 3;

    __syncthreads();                       // lead: prior stage's images settled
    f32x4 accA[4][4], accX[4][4];
#pragma unroll
    for (int m = 0; m < 4; ++m)
#pragma unroll
        for (int q = 0; q < 4; ++q) {
            accA[m][q] = (f32x4){0.f, 0.f, 0.f, 0.f};
            accX[m][q] = (f32x4){0.f, 0.f, 0.f, 0.f};
        }
#pragma unroll
    for (int kb = 0; kb < 8; ++kb) {
        s16x8 afA[4], afX[4], bfA[4], bfX[4];
#pragma unroll
        for (int m = 0; m < 4; ++m) {
            int ci = (kb * 8 + wr * 4 + m) * 64 + lane;
            afA[m] = *(const s16x8*)(srcA + ci * 8);
            if constexpr (!SHARED) afX[m] = *(const s16x8*)(srcX + ci * 8);
        }
#pragma unroll
        for (int q = 0; q < 4; ++q) {
            int cn = (q >> 1) * 8 + wc * 2 + (q & 1);
            bfA[q] = *(const s16x8*)(WpA + (size_t)((kb * 16 + cn) * 64 + lane) * 8);
            bfX[q] = *(const s16x8*)(WpX + (size_t)((kb * 16 + cn) * 64 + lane) * 8);
        }
#pragma unroll
        for (int m = 0; m < 4; ++m)
#pragma unroll
            for (int q = 0; q < 4; ++q) {
                accA[m][q] = __builtin_amdgcn_mfma_f32_16x16x32_f16(ash(afA[m]), ash(bfA[q]), accA[m][q], 0, 0, 0);
                if constexpr (SHARED)
                    accX[m][q] = __builtin_amdgcn_mfma_f32_16x16x32_f16(ash(afA[m]), ash(bfX[q]), accX[m][q], 0, 0, 0);
                else
                    accX[m][q] = __builtin_amdgcn_mfma_f32_16x16x32_f16(ash(afX[m]), ash(bfX[q]), accX[m][q], 0, 0, 0);
            }
    }
    half_phase<MODE_A>(accA, 0, dstA, bh, agf, biasA, tid);
    half_phase<MODE_A>(accA, 1, dstA, bh, agf, biasA, tid);
    half_phase<MODE_X>(accX, 0, dstX, bh, agf, biasX, tid);
    half_phase<MODE_X>(accX, 1, dstX, bh, agf, biasX, tid);
}

// ---------------- mega kernel: 512 thr, 1 block/graph, all stages in LDS ----

__global__ __launch_bounds__(512, 1) void k_mega(
    const float* __restrict__ Xf, const unsigned* __restrict__ ebuf,
    const int* __restrict__ pos,
    const short* __restrict__ Wp, const float* __restrict__ Wlp,
    const float* __restrict__ ba1, const float* __restrict__ bx1,
    const float* __restrict__ bx2, const float* __restrict__ bl,
    float* __restrict__ out)
{
    __shared__ __align__(16) char lds[163840];
    short* scA  = (short*)lds;               // 64 KB: X image -> x1 -> x2
    short* keep = (short*)(lds + 65536);     // 64 KB: a1 image -> a2 image
    short* bh   = (short*)(lds + 131072);    // 32 KB: H half / reduce scratch
    float* Ab   = (float*)(lds + 65536);     // build alias (spans keep + bh head)
    float* degb = (float*)(lds + 133120);    // build alias: deg/dinv[128]

    const int tid = threadIdx.x;
    const int g = blockIdx.x;
    const int lane = tid & 63, w = tid >> 6, pr4 = w >> 1;
    const int lq = lane >> 4, lm = lane & 15;

    // ---- issue X loads early: 8 x 32B per thread into registers ----
    const float* xg = Xf + (size_t)g * NPG * 256;
    f32x4 xv[8][2];
#pragma unroll
    for (int it = 0; it < 8; ++it) {
        int i = tid + it * 512;
        int lane_ = i & 63, grp = i >> 6;
        int rb = grp & 7, kb = grp >> 3;
        int row = rb * 16 + (lane_ & 15);
        int k0 = kb * 32 + (lane_ >> 4) * 8;
        const float* p = xg + (size_t)row * 256 + k0;
        xv[it][0] = *(const f32x4*)p;
        xv[it][1] = *(const f32x4*)(p + 4);
    }

    // ---- build normalized adjacency in LDS (Ab aliases keep) ----
    for (int i = tid; i < 4224; i += 512) ((f32x4*)Ab)[i] = (f32x4){0.f, 0.f, 0.f, 0.f};
    if (tid < 128) degb[tid] = 0.f;
    int cnt = pos[g]; if (cnt > 2048) cnt = 2048;
    const unsigned* eb = ebuf + g * 2048;
    __syncthreads();
    for (int i = tid; i < cnt; i += 512) atomicAdd(&degb[eb[i] >> 8], 1.0f);
    __syncthreads();
    if (tid < 128) degb[tid] = rsqrtf(degb[tid] + 1.0f);
    __syncthreads();
    for (int i = tid; i < cnt; i += 512) {
        unsigned ew = eb[i];
        int ii = ew >> 8, jj = ew & 127;
        atomicAdd(&Ab[ii * 132 + jj], degb[ii] * degb[jj]);
    }
    if (tid < 128) atomicAdd(&Ab[tid * 132 + tid], degb[tid] * degb[tid]);

    // ---- store X image into scA (loads landed; disjoint from Ab region) ----
#pragma unroll
    for (int it = 0; it < 8; ++it) {
        int i = tid + it * 512;
        s16x8 o;
        o[0]=f2h(xv[it][0][0]); o[1]=f2h(xv[it][0][1]);
        o[2]=f2h(xv[it][0][2]); o[3]=f2h(xv[it][0][3]);
        o[4]=f2h(xv[it][1][0]); o[5]=f2h(xv[it][1][1]);
        o[6]=f2h(xv[it][1][2]); o[7]=f2h(xv[it][1][3]);
        *(s16x8*)(scA + (size_t)i * 8) = o;
    }
    __syncthreads();                       // Ab complete + X image complete

    s16x8 agf[2][4];
#pragma unroll
    for (int m = 0; m < 2; ++m)
#pragma unroll
        for (int kb = 0; kb < 4; ++kb) {
            int r = pr4 * 32 + m * 16 + lm;
            const float* ap = Ab + r * 132 + kb * 32 + lq * 8;
            f32x4 a0 = *(const f32x4*)ap, a1 = *(const f32x4*)(ap + 4);
            s16x8 o;
            o[0]=f2h(a0[0]); o[1]=f2h(a0[1]); o[2]=f2h(a0[2]); o[3]=f2h(a0[3]);
            o[4]=f2h(a1[0]); o[5]=f2h(a1[1]); o[6]=f2h(a1[2]); o[7]=f2h(a1[3]);
            agf[m][kb] = o;
        }
    // conv_merged's lead barrier ensures all waves extracted before keep is written

    // merged stage A (s0+s2): a1 = relu(X@Wa1+A), x1 = relu(X@Wx1+A); shared X
    conv_merged<0, 0, true >(scA, scA, keep, scA, bh,
                             Wp + (size_t)0 * 65536, Wp + (size_t)2 * 65536,
                             agf, ba1, bx1, tid);
    // merged stage B (s1+s3): a2 = softmax(a1@Wa2+A), x2 = relu(x1@Wx2+A)
    conv_merged<1, 2, false>(keep, scA, keep, scA, bh,
                             Wp + (size_t)1 * 65536, Wp + (size_t)3 * 65536,
                             agf, nullptr, bx2, tid);

    // ---- bmm P = a2^T @ x2 fused with Wl reduce + final softmax ----
    __syncthreads();
    s16x8 pa[2][4];
#pragma unroll
    for (int dt = 0; dt < 2; ++dt)
#pragma unroll
        for (int kb = 0; kb < 4; ++kb)
            pa[dt][kb] = *(const s16x8*)(keep + (((w * 2 + dt) * 4 + kb) * 64 + lane) * 8);
    float p0 = 0.f, p1 = 0.f;
    for (int et = 0; et < 16; ++et) {
        s16x8 xb[4];
#pragma unroll
        for (int kb = 0; kb < 4; ++kb)
            xb[kb] = *(const s16x8*)(scA + ((et * 4 + kb) * 64 + lane) * 8);
#pragma unroll
        for (int dt = 0; dt < 2; ++dt) {
            f32x4 a = (f32x4){0.f, 0.f, 0.f, 0.f};
#pragma unroll
            for (int kb = 0; kb < 4; ++kb)
                a = __builtin_amdgcn_mfma_f32_16x16x32_f16(ash(pa[dt][kb]), ash(xb[kb]), a, 0, 0, 0);
            const float* wl = Wlp + ((((size_t)w * 2 + dt) * 16 + et) * 64 + lane) * 8;
            f32x4 w0 = *(const f32x4*)wl;
            f32x4 w1 = *(const f32x4*)(wl + 4);
            p0 += a[0] * w0[0] + a[1] * w0[2] + a[2] * w1[0] + a[3] * w1[2];
            p1 += a[0] * w0[1] + a[1] * w0[3] + a[2] * w1[1] + a[3] * w1[3];
        }
    }
#pragma unroll
    for (int off = 32; off > 0; off >>= 1) {
        p0 += __shfl_xor(p0, off);
        p1 += __shfl_xor(p1, off);
    }
    float* red = (float*)bh;
    if (lane == 0) { red[w] = p0; red[8 + w] = p1; }
    __syncthreads();
    if (tid == 0) {
        float l0 = bl[0], l1 = bl[1];
#pragma unroll
        for (int i = 0; i < 8; ++i) { l0 += red[i]; l1 += red[8 + i]; }
        float mm = fmaxf(l0, l1);
        float e0 = __expf(l0 - mm), e1 = __expf(l1 - mm);
        float inv = 1.0f / (e0 + e1);
        out[g * 2 + 0] = e0 * inv;
        out[g * 2 + 1] = e1 * inv;
    }
}

// ---------------- launcher ----------------

extern "C" void kernel_launch(void* const* d_in, const int* in_sizes, int n_in,
                              void* d_out, int out_size, void* d_ws, size_t ws_size,
                              hipStream_t stream) {
    const float* x   = (const float*)d_in[0];
    const int*   ei  = (const int*)d_in[1];
    const float* Wa1 = (const float*)d_in[3];
    const float* ba1 = (const float*)d_in[4];
    const float* Wa2 = (const float*)d_in[5];
    const float* Wx1 = (const float*)d_in[7];
    const float* bx1 = (const float*)d_in[8];
    const float* Wx2 = (const float*)d_in[9];
    const float* bx2 = (const float*)d_in[10];
    const float* Wl  = (const float*)d_in[11];
    const float* bl  = (const float*)d_in[12];
    float* out = (float*)d_out;

    char* ws = (char*)d_ws;
    int*      pos  = (int*)(ws + 0);           // 4 KB slot
    unsigned* ebuf = (unsigned*)(ws + 4096);   // 2 MB
    short*    Wpk  = (short*)(ws + 2101248);   // 512 KB
    float*    Wlp  = (float*)(ws + 2625536);   // 512 KB
    if (ws_size < 3149824) return;

    hipMemsetAsync(pos, 0, 1024, stream);
    k_pre<<<112, 1024, 0, stream>>>(ei, pos, ebuf, Wa1, Wa2, Wx1, Wx2, Wl, Wpk, Wlp);
    k_mega<<<GG, 512, 0, stream>>>(x, ebuf, pos, Wpk, Wlp, ba1, bx1, bx2, bl, out);
}

// Round 19
// 57.705 us; speedup vs baseline: 1.1362x; 1.1362x over previous
//
#include <hip/hip_runtime.h>
#include <hip/hip_bf16.h>

#define NN 32768
#define GG 256
#define NPG 128
#define EE 262144

using s16x4 = __attribute__((ext_vector_type(4))) short;
using s16x8 = __attribute__((ext_vector_type(8))) short;
using f16x8 = __attribute__((ext_vector_type(8))) _Float16;
using f32x4 = __attribute__((ext_vector_type(4))) float;

__device__ __forceinline__ short f2h(float f) {
    _Float16 h = (_Float16)f;
    return __builtin_bit_cast(short, h);
}
__device__ __forceinline__ f16x8 ash(s16x8 v) { return __builtin_bit_cast(f16x8, v); }

// ---------------- pre-pass: edge bucketing + W/Wl pack (112 blocks) ---------
// blocks 0..63: hierarchical edge scatter; 64..95: W B-frag; 96..111: Wl.
// B-frag chunk: ci=(kb*16+cn)*64+lane, lane=(c%16)|(((k%32)/8)<<4), elem=k%8

__global__ __launch_bounds__(1024) void k_pre(
    const int* __restrict__ ei, int* __restrict__ pos, unsigned* __restrict__ ebuf,
    const float* __restrict__ W0, const float* __restrict__ W1,
    const float* __restrict__ W2, const float* __restrict__ W3,
    const float* __restrict__ Wl,
    short* __restrict__ Wp, float* __restrict__ Wlp)
{
    const int b = blockIdx.x;
    const int tid = threadIdx.x;
    if (b < 64) {
        __shared__ int cnt[256];
        __shared__ int base[256];
        if (tid < 256) cnt[tid] = 0;
        __syncthreads();
        int g[4], r[4];
        unsigned pk[4];
#pragma unroll
        for (int it = 0; it < 4; ++it) {
            int e = b * 4096 + it * 1024 + tid;
            int s = ei[e], d = ei[EE + e];
            g[it] = d >> 7;
            pk[it] = (unsigned)(((d & 127) << 8) | (s & 127));
            r[it] = atomicAdd(&cnt[g[it]], 1);
        }
        __syncthreads();
        if (tid < 256) {
            int c = cnt[tid];
            base[tid] = (c > 0) ? atomicAdd(&pos[tid], c) : 0;
        }
        __syncthreads();
#pragma unroll
        for (int it = 0; it < 4; ++it) {
            int p = base[g[it]] + r[it];
            if (p < 2048) ebuf[g[it] * 2048 + p] = pk[it];
        }
    } else if (b < 96) {
        int t = (b - 64) * 1024 + tid;           // 32768
        int mat = t >> 13, ci = t & 8191;
        const float* W = (mat == 0) ? W0 : (mat == 1) ? W1 : (mat == 2) ? W2 : W3;
        int lane = ci & 63, t2 = ci >> 6;
        int cn = t2 & 15, kb = t2 >> 4;
        int c = cn * 16 + (lane & 15);
        int k0 = kb * 32 + (lane >> 4) * 8;
        s16x8 o;
#pragma unroll
        for (int j = 0; j < 8; ++j) o[j] = f2h(W[(size_t)(k0 + j) * 256 + c]);
        *(s16x8*)(Wp + ((size_t)mat * 8192 + ci) * 8) = o;
    } else {
        int t = (b - 96) * 1024 + tid;           // 16384
        int lane = t & 63, tile = t >> 6;
        int db = tile >> 4, eb = tile & 15;
        int q = lane >> 4, ce = lane & 15;
        float* dst = Wlp + (size_t)t * 8;
#pragma unroll
        for (int r = 0; r < 4; ++r)
#pragma unroll
            for (int cls = 0; cls < 2; ++cls)
                dst[r * 2 + cls] = Wl[(((size_t)(db * 16 + q * 4 + r) * 256) + eb * 16 + ce) * 2 + cls];
    }
}

// ---------------- conv stage, half-H (r12-proven), LDS source always --------
// 8 waves. GEMM full H in regs acc[4][4]; per cb-half: scatter -> bh, PROP 4x2.
// In-place (dstImg == scSrc) is safe: all GEMM source reads complete before
// the first cb-loop barrier; dstImg writes happen after it.
// MODE 0: bias+relu -> act A-frag image in dstImg
// MODE 1: raw conv -> no-max register softmax -> B-frag image in dstImg
// MODE 2: bias+relu -> B-frag image in dstImg

template<int MODE>
__device__ __forceinline__ void conv_stage6(
    const short* scSrc, short* dstImg, short* bh,
    const short* __restrict__ Wp, const s16x8 (&agf)[2][4],
    const float* __restrict__ bias, int tid)
{
    const int lane = tid & 63, w = tid >> 6, wr = w >> 2, wc = w & 3;
    const int lq = lane >> 4, lm = lane & 15;

    __syncthreads();                       // prior stage's dstImg writes visible
    f32x4 acc[4][4];
#pragma unroll
    for (int m = 0; m < 4; ++m)
#pragma unroll
        for (int q = 0; q < 4; ++q) acc[m][q] = (f32x4){0.f, 0.f, 0.f, 0.f};
#pragma unroll
    for (int kb = 0; kb < 8; ++kb) {
        s16x8 af[4], bf[4];
#pragma unroll
        for (int m = 0; m < 4; ++m) {
            int ci = (kb * 8 + wr * 4 + m) * 64 + lane;
            af[m] = *(const s16x8*)(scSrc + ci * 8);
        }
#pragma unroll
        for (int q = 0; q < 4; ++q) {
            int cn = (q >> 1) * 8 + wc * 2 + (q & 1);
            bf[q] = *(const s16x8*)(Wp + (size_t)((kb * 16 + cn) * 64 + lane) * 8);
        }
#pragma unroll
        for (int m = 0; m < 4; ++m)
#pragma unroll
            for (int q = 0; q < 4; ++q)
                acc[m][q] = __builtin_amdgcn_mfma_f32_16x16x32_f16(ash(af[m]), ash(bf[q]), acc[m][q], 0, 0, 0);
    }
    // rows nr = wr*64 + m*16 + lq*4 + r ; cols cg(q) = (q>>1)*128 + wc*32 + (q&1)*16 + lm

#pragma unroll
    for (int cb = 0; cb < 2; ++cb) {
        __syncthreads();                   // bh free (and GEMM reads all done)
#pragma unroll
        for (int m = 0; m < 4; ++m)
#pragma unroll
            for (int n = 0; n < 2; ++n) {
                f32x4 hv4 = acc[m][cb * 2 + n];
                int c = wc * 32 + n * 16 + lm;
                int rhi = wr * 2 + (m >> 1);
                int rmid = (m & 1) * 2 + (lq >> 1);
                int idx = ((c >> 4) * 4 + rhi) * 64 + (lm | (rmid << 4));
                s16x4 hv;
                hv[0] = f2h(hv4[0]); hv[1] = f2h(hv4[1]);
                hv[2] = f2h(hv4[2]); hv[3] = f2h(hv4[3]);
                *(s16x4*)&bh[idx * 8 + (lq & 1) * 4] = hv;
            }
        __syncthreads();
        const int pr4 = w >> 1, pc2 = w & 1;
        f32x4 acc2[2][4];
#pragma unroll
        for (int m = 0; m < 2; ++m)
#pragma unroll
            for (int n = 0; n < 4; ++n) acc2[m][n] = (f32x4){0.f, 0.f, 0.f, 0.f};
#pragma unroll
        for (int kb = 0; kb < 4; ++kb) {
            s16x8 bf2[4];
#pragma unroll
            for (int n = 0; n < 4; ++n)
                bf2[n] = *(const s16x8*)(bh + (((pc2 * 4 + n) * 4 + kb) * 64 + lane) * 8);
#pragma unroll
            for (int m = 0; m < 2; ++m)
#pragma unroll
                for (int n = 0; n < 4; ++n)
                    acc2[m][n] = __builtin_amdgcn_mfma_f32_16x16x32_f16(ash(agf[m][kb]), ash(bf2[n]), acc2[m][n], 0, 0, 0);
        }
        // rows nr = pr4*32 + m*16 + lq*4 + r ; cols cg = cb*128 + pc2*64 + n*16 + lm

        if constexpr (MODE == 0) {
#pragma unroll
            for (int m = 0; m < 2; ++m)
#pragma unroll
                for (int n = 0; n < 4; ++n) {
                    float bn = bias[cb * 128 + pc2 * 64 + n * 16 + lm];
#pragma unroll
                    for (int r = 0; r < 4; ++r) {
                        float v = fmaxf(acc2[m][n][r] + bn, 0.f);
                        int nr = pr4 * 32 + m * 16 + lq * 4 + r;
                        int cg = cb * 128 + pc2 * 64 + n * 16 + lm;
                        int idx = ((cg >> 5) * 8 + (nr >> 4)) * 64 + ((nr & 15) | (((cg & 31) >> 3) << 4));
                        dstImg[idx * 8 + (cg & 7)] = f2h(v);
                    }
                }
        } else if constexpr (MODE == 2) {
#pragma unroll
            for (int m = 0; m < 2; ++m)
#pragma unroll
                for (int n = 0; n < 4; ++n) {
                    float bn = bias[cb * 128 + pc2 * 64 + n * 16 + lm];
                    s16x4 ov;
#pragma unroll
                    for (int r = 0; r < 4; ++r) ov[r] = f2h(fmaxf(acc2[m][n][r] + bn, 0.f));
                    int cn2 = cb * 8 + pc2 * 4 + n;
                    int chunk = (cn2 * 4 + pr4) * 64 + (lm | ((m * 2 + (lq >> 1)) << 4));
                    *(s16x4*)(dstImg + chunk * 8 + (lq & 1) * 4) = ov;
                }
        } else {  // MODE 1: segment-softmax, no max subtraction (values bounded)
            __syncthreads();               // PROP bh reads done -> red usable
            float* red = (float*)bh;
            float ev[2][4][4];
            float ps[4] = {0.f, 0.f, 0.f, 0.f};
#pragma unroll
            for (int m = 0; m < 2; ++m)
#pragma unroll
                for (int n = 0; n < 4; ++n)
#pragma unroll
                    for (int r = 0; r < 4; ++r) {
                        float e = __expf(acc2[m][n][r]);
                        ev[m][n][r] = e; ps[n] += e;
                    }
#pragma unroll
            for (int n = 0; n < 4; ++n) {
                ps[n] += __shfl_xor(ps[n], 16);
                ps[n] += __shfl_xor(ps[n], 32);
            }
            const int pr4_ = w >> 1, pc2_ = w & 1;
            if (lq == 0) {
#pragma unroll
                for (int n = 0; n < 4; ++n)
                    red[pr4_ * 128 + pc2_ * 64 + n * 16 + lm] = ps[n];
            }
            __syncthreads();
#pragma unroll
            for (int m = 0; m < 2; ++m)
#pragma unroll
                for (int n = 0; n < 4; ++n) {
                    int c = pc2_ * 64 + n * 16 + lm;
                    float sinv = 1.0f / (red[c] + red[128 + c] + red[256 + c] + red[384 + c]);
                    s16x4 ov;
#pragma unroll
                    for (int r = 0; r < 4; ++r) ov[r] = f2h(ev[m][n][r] * sinv);
                    int cn2 = cb * 8 + pc2_ * 4 + n;
                    int chunk = (cn2 * 4 + pr4_) * 64 + (lm | ((m * 2 + (lq >> 1)) << 4));
                    *(s16x4*)(dstImg + chunk * 8 + (lq & 1) * 4) = ov;
                }
        }
    }
}

// ---------------- mega kernel: 512 thr, 1 block/graph, all stages in LDS ----
// Build overlap: Ab aliases keep+bh-head (dead during build); X loads issued
// into registers BEFORE the atomic passes so HBM latency drains under them.
// Stage order s0 (X->a1), s2 (X->x1), s1 (a1->a2), s3 (x1->x2): X liveness
// ends at s2 so 5 images fit 2 buffers via in-place overwrites.

__global__ __launch_bounds__(512, 1) void k_mega(
    const float* __restrict__ Xf, const unsigned* __restrict__ ebuf,
    const int* __restrict__ pos,
    const short* __restrict__ Wp, const float* __restrict__ Wlp,
    const float* __restrict__ ba1, const float* __restrict__ bx1,
    const float* __restrict__ bx2, const float* __restrict__ bl,
    float* __restrict__ out)
{
    __shared__ __align__(16) char lds[163840];
    short* scA  = (short*)lds;               // 64 KB: X image -> x1 -> x2
    short* keep = (short*)(lds + 65536);     // 64 KB: a1 image -> a2 image
    short* bh   = (short*)(lds + 131072);    // 32 KB: H half / reduce scratch
    float* Ab   = (float*)(lds + 65536);     // build alias (spans keep + bh head)
    float* degb = (float*)(lds + 133120);    // build alias: deg/dinv[128]

    const int tid = threadIdx.x;
    const int g = blockIdx.x;
    const int lane = tid & 63, w = tid >> 6, pr4 = w >> 1;
    const int lq = lane >> 4, lm = lane & 15;

    // ---- issue X loads early: 8 x 32B per thread into registers ----
    const float* xg = Xf + (size_t)g * NPG * 256;
    f32x4 xv[8][2];
#pragma unroll
    for (int it = 0; it < 8; ++it) {
        int i = tid + it * 512;
        int lane_ = i & 63, grp = i >> 6;
        int rb = grp & 7, kb = grp >> 3;
        int row = rb * 16 + (lane_ & 15);
        int k0 = kb * 32 + (lane_ >> 4) * 8;
        const float* p = xg + (size_t)row * 256 + k0;
        xv[it][0] = *(const f32x4*)p;
        xv[it][1] = *(const f32x4*)(p + 4);
    }

    // ---- build normalized adjacency in LDS (Ab aliases keep) ----
    for (int i = tid; i < 4224; i += 512) ((f32x4*)Ab)[i] = (f32x4){0.f, 0.f, 0.f, 0.f};
    if (tid < 128) degb[tid] = 0.f;
    int cnt = pos[g]; if (cnt > 2048) cnt = 2048;
    const unsigned* eb = ebuf + g * 2048;
    __syncthreads();
    for (int i = tid; i < cnt; i += 512) atomicAdd(&degb[eb[i] >> 8], 1.0f);
    __syncthreads();
    if (tid < 128) degb[tid] = rsqrtf(degb[tid] + 1.0f);
    __syncthreads();
    for (int i = tid; i < cnt; i += 512) {
        unsigned ew = eb[i];
        int ii = ew >> 8, jj = ew & 127;
        atomicAdd(&Ab[ii * 132 + jj], degb[ii] * degb[jj]);
    }
    if (tid < 128) atomicAdd(&Ab[tid * 132 + tid], degb[tid] * degb[tid]);

    // ---- store X image into scA (loads have long landed; disjoint from Ab) ----
#pragma unroll
    for (int it = 0; it < 8; ++it) {
        int i = tid + it * 512;
        s16x8 o;
        o[0]=f2h(xv[it][0][0]); o[1]=f2h(xv[it][0][1]);
        o[2]=f2h(xv[it][0][2]); o[3]=f2h(xv[it][0][3]);
        o[4]=f2h(xv[it][1][0]); o[5]=f2h(xv[it][1][1]);
        o[6]=f2h(xv[it][1][2]); o[7]=f2h(xv[it][1][3]);
        *(s16x8*)(scA + (size_t)i * 8) = o;
    }
    __syncthreads();                       // Ab complete + X image complete

    s16x8 agf[2][4];
#pragma unroll
    for (int m = 0; m < 2; ++m)
#pragma unroll
        for (int kb = 0; kb < 4; ++kb) {
            int r = pr4 * 32 + m * 16 + lm;
            const float* ap = Ab + r * 132 + kb * 32 + lq * 8;
            f32x4 a0 = *(const f32x4*)ap, a1 = *(const f32x4*)(ap + 4);
            s16x8 o;
            o[0]=f2h(a0[0]); o[1]=f2h(a0[1]); o[2]=f2h(a0[2]); o[3]=f2h(a0[3]);
            o[4]=f2h(a1[0]); o[5]=f2h(a1[1]); o[6]=f2h(a1[2]); o[7]=f2h(a1[3]);
            agf[m][kb] = o;
        }
    // conv_stage6's leading __syncthreads ensures all waves extracted before
    // s0 writes keep (= Ab region)

    // s0: a1 = relu(conv(X, Wa1));  X (scA) -> a1 (keep)
    conv_stage6<0>(scA,  keep, bh, Wp + (size_t)0 * 65536, agf, ba1, tid);
    // s2: x1 = relu(conv(X, Wx1));  X (scA) -> x1 (scA, in place)
    conv_stage6<0>(scA,  scA,  bh, Wp + (size_t)2 * 65536, agf, bx1, tid);
    // s1: a2 = softmax(conv(a1, Wa2)); a1 (keep) -> a2 B-frag (keep, in place)
    conv_stage6<1>(keep, keep, bh, Wp + (size_t)1 * 65536, agf, nullptr, tid);
    // s3: x2 = relu(conv(x1, Wx2)); x1 (scA) -> x2 B-frag (scA, in place)
    conv_stage6<2>(scA,  scA,  bh, Wp + (size_t)3 * 65536, agf, bx2, tid);

    // ---- bmm P = a2^T @ x2 fused with Wl reduce + final softmax ----
    __syncthreads();
    s16x8 pa[2][4];
#pragma unroll
    for (int dt = 0; dt < 2; ++dt)
#pragma unroll
        for (int kb = 0; kb < 4; ++kb)
            pa[dt][kb] = *(const s16x8*)(keep + (((w * 2 + dt) * 4 + kb) * 64 + lane) * 8);
    float p0 = 0.f, p1 = 0.f;
    for (int et = 0; et < 16; ++et) {
        s16x8 xb[4];
#pragma unroll
        for (int kb = 0; kb < 4; ++kb)
            xb[kb] = *(const s16x8*)(scA + ((et * 4 + kb) * 64 + lane) * 8);
#pragma unroll
        for (int dt = 0; dt < 2; ++dt) {
            f32x4 a = (f32x4){0.f, 0.f, 0.f, 0.f};
#pragma unroll
            for (int kb = 0; kb < 4; ++kb)
                a = __builtin_amdgcn_mfma_f32_16x16x32_f16(ash(pa[dt][kb]), ash(xb[kb]), a, 0, 0, 0);
            const float* wl = Wlp + ((((size_t)w * 2 + dt) * 16 + et) * 64 + lane) * 8;
            f32x4 w0 = *(const f32x4*)wl;
            f32x4 w1 = *(const f32x4*)(wl + 4);
            p0 += a[0] * w0[0] + a[1] * w0[2] + a[2] * w1[0] + a[3] * w1[2];
            p1 += a[0] * w0[1] + a[1] * w0[3] + a[2] * w1[1] + a[3] * w1[3];
        }
    }
#pragma unroll
    for (int off = 32; off > 0; off >>= 1) {
        p0 += __shfl_xor(p0, off);
        p1 += __shfl_xor(p1, off);
    }
    float* red = (float*)bh;
    if (lane == 0) { red[w] = p0; red[8 + w] = p1; }
    __syncthreads();
    if (tid == 0) {
        float l0 = bl[0], l1 = bl[1];
#pragma unroll
        for (int i = 0; i < 8; ++i) { l0 += red[i]; l1 += red[8 + i]; }
        float mm = fmaxf(l0, l1);
        float e0 = __expf(l0 - mm), e1 = __expf(l1 - mm);
        float inv = 1.0f / (e0 + e1);
        out[g * 2 + 0] = e0 * inv;
        out[g * 2 + 1] = e1 * inv;
    }
}

// ---------------- launcher ----------------

extern "C" void kernel_launch(void* const* d_in, const int* in_sizes, int n_in,
                              void* d_out, int out_size, void* d_ws, size_t ws_size,
                              hipStream_t stream) {
    const float* x   = (const float*)d_in[0];
    const int*   ei  = (const int*)d_in[1];
    const float* Wa1 = (const float*)d_in[3];
    const float* ba1 = (const float*)d_in[4];
    const float* Wa2 = (const float*)d_in[5];
    const float* Wx1 = (const float*)d_in[7];
    const float* bx1 = (const float*)d_in[8];
    const float* Wx2 = (const float*)d_in[9];
    const float* bx2 = (const float*)d_in[10];
    const float* Wl  = (const float*)d_in[11];
    const float* bl  = (const float*)d_in[12];
    float* out = (float*)d_out;

    char* ws = (char*)d_ws;
    int*      pos  = (int*)(ws + 0);           // 4 KB slot
    unsigned* ebuf = (unsigned*)(ws + 4096);   // 2 MB
    short*    Wpk  = (short*)(ws + 2101248);   // 512 KB
    float*    Wlp  = (float*)(ws + 2625536);   // 512 KB
    if (ws_size < 3149824) return;

    hipMemsetAsync(pos, 0, 1024, stream);
    k_pre<<<112, 1024, 0, stream>>>(ei, pos, ebuf, Wa1, Wa2, Wx1, Wx2, Wl, Wpk, Wlp);
    k_mega<<<GG, 512, 0, stream>>>(x, ebuf, pos, Wpk, Wlp, ba1, bx1, bx2, bl, out);
}